// Round 9
// baseline (197.891 us; speedup 1.0000x reference)
//
#include <hip/hip_runtime.h>

// Problem constants (B=8, S=4096, D=64, ds=16)
#define BATCH   8
#define SEQ     4096
#define DM      64
#define DS      16
#define BS      (BATCH*SEQ)      // 32768 timesteps
#define CHUNK   16               // scan chunk length
#define NCHT    (BS/CHUNK)       // 2048 chunks total (256 per batch)
#define SG      16               // chunks per supergroup
#define NSG     (NCHT/SG)        // 128 supergroups (16 per batch)

typedef __attribute__((ext_vector_type(8))) __bf16 bf16x8;
typedef __attribute__((ext_vector_type(4))) float  f32x4;

__device__ __forceinline__ unsigned short f2bf(float f) {
  unsigned int u = __float_as_uint(f);
  u += 0x7fffu + ((u >> 16) & 1u);          // RNE (finite values)
  return (unsigned short)(u >> 16);
}
__device__ __forceinline__ float bflo(unsigned int u) { return __uint_as_float(u << 16); }
__device__ __forceinline__ float bfhi(unsigned int u) { return __uint_as_float(u & 0xffff0000u); }

// LDS A-tile strides (ushorts): per-i 20 (40B), per-t 324 (648B)
#define AS_I 20
#define AS_T 324

// ---------------------------------------------------------------------------
// K0: cast + PACK weights (unchanged).
// ---------------------------------------------------------------------------
__global__ __launch_bounds__(256) void k0_castw(
    const float* __restrict__ WA, const float* __restrict__ WB,
    const float* __restrict__ WC,
    unsigned short* __restrict__ WBApk, unsigned short* __restrict__ WCpk)
{
  const int o = blockIdx.x * 256 + threadIdx.x;
  if (o < 81920) {
    int idx = o;
    const int e = idx & 7;    idx >>= 3;
    const int f = idx % 10;   idx /= 10;
    const int quad = idx & 3; idx >>= 2;
    const int l15 = idx & 15; idx >>= 4;
    const int n = idx;                      // 0..15
    float src;
    if (f < 8) {
      const int r = f >> 1, h = f & 1;
      src = WB[(h * 32 + quad * 8 + e) * 1024 + (n * 4 + r) * 16 + l15];
    } else {
      const int h = f - 8;
      src = WA[(h * 32 + quad * 8 + e) * 256 + n * 16 + l15];
    }
    WBApk[o] = f2bf(src);
  } else {
    const int p = o - 81920;                // 0..65535
    const int e = p & 7;
    const int h = (p >> 3) & 1;
    const int quad = (p >> 4) & 3;
    const int l15 = (p >> 6) & 15;
    const int nr = p >> 10;                 // n*4+rc, 0..63
    WCpk[p] = f2bf(WC[(h * 32 + quad * 8 + e) * 1024 + nr * 16 + l15]);
  }
}

// Weight-fragment bundle for one n-iteration of the merged B/A loop.
struct WFrag {
  bf16x8 b00, b01, b10, b11, b20, b21, b30, b31;  // WB frags, r=0..3 x 2 halves
  bf16x8 a0f, a1f;                                 // WA frags
  float  ba;                                       // bA bias
};

__device__ __forceinline__ WFrag loadw(
    const unsigned short* __restrict__ WBApk,
    const float* __restrict__ bA, int n, int l15, int quad)
{
  WFrag f;
  const bf16x8* fp = (const bf16x8*)(WBApk + (size_t)((n * 16 + l15) * 4 + quad) * 80);
  f.b00 = fp[0]; f.b01 = fp[1];
  f.b10 = fp[2]; f.b11 = fp[3];
  f.b20 = fp[4]; f.b21 = fp[5];
  f.b30 = fp[6]; f.b31 = fp[7];
  f.a0f = fp[8]; f.a1f = fp[9];
  f.ba  = bA[n * 16 + l15];
  return f;
}

// ---------------------------------------------------------------------------
// G1A: GEMM phase (unchanged).
// ---------------------------------------------------------------------------
__global__ __launch_bounds__(256, 4) void g1a(
    const float* __restrict__ x, const unsigned short* __restrict__ WBApk,
    const float* __restrict__ bB, const float* __restrict__ bA,
    unsigned short* __restrict__ xb, unsigned short* __restrict__ Wt_ws,
    float* __restrict__ u_ws)
{
  __shared__ __align__(16) float xs[32][68];                //  8704 B
  __shared__ __align__(16) float bBs[1024];                 //  4096 B
  __shared__ __align__(16) unsigned short As[32 * AS_T];    // 20736 B
  __shared__ __align__(16) float bxs[32][16];               //  2048 B

  const int tid  = threadIdx.x;
  const int lane = tid & 63;
  const int l15  = lane & 15;
  const int quad = lane >> 4;
  const int w    = tid >> 6;             // 0..3
  const int tg   = w >> 1;               // t-half
  const int nh   = w & 1;                // n-half
  const int t0   = blockIdx.x * 32;
  const int twl  = tg * 16;
  const int n0   = nh * 8;

  { // stage fp32 x tile (32x64 = 512 float4) + bB (256 float4)
    const float4* xg = (const float4*)(x + (size_t)t0 * DM);
    #pragma unroll
    for (int i = 0; i < 2; ++i) {
      const int f4 = tid + 256 * i;
      ((float4*)&xs[f4 >> 4][0])[f4 & 15] = xg[f4];
    }
    ((float4*)bBs)[tid] = ((const float4*)bB)[tid];
  }
  __syncthreads();

  // issue first weight-fragment bundle so it overlaps the frag build below
  WFrag cur = loadw(WBApk, bA, n0, l15, quad);

  // ---- build A-operand frags from LDS; store to xb for g2 (nh==0 only) ----
  bf16x8 a0, a1;
  {
    const int row = twl + l15;
    union { bf16x8 v; ushort4 s[2]; } ua, ub;
    float4 p0 = *(const float4*)&xs[row][quad * 8];
    float4 p1 = *(const float4*)&xs[row][quad * 8 + 4];
    float4 p2 = *(const float4*)&xs[row][32 + quad * 8];
    float4 p3 = *(const float4*)&xs[row][32 + quad * 8 + 4];
    ua.s[0] = (ushort4){f2bf(p0.x), f2bf(p0.y), f2bf(p0.z), f2bf(p0.w)};
    ua.s[1] = (ushort4){f2bf(p1.x), f2bf(p1.y), f2bf(p1.z), f2bf(p1.w)};
    ub.s[0] = (ushort4){f2bf(p2.x), f2bf(p2.y), f2bf(p2.z), f2bf(p2.w)};
    ub.s[1] = (ushort4){f2bf(p3.x), f2bf(p3.y), f2bf(p3.z), f2bf(p3.w)};
    a0 = ua.v; a1 = ub.v;
    if (nh == 0) {
      unsigned short* xp = xb + (size_t)(t0 + row) * 64 + quad * 8;
      *(bf16x8*)xp        = a0;
      *(bf16x8*)(xp + 32) = a1;
    }
  }

  // hoist B-epilogue x values (constant across n): xv[r][reg]
  float xv[4][4];
  #pragma unroll
  for (int r = 0; r < 4; ++r)
    #pragma unroll
    for (int reg = 0; reg < 4; ++reg)
      xv[r][reg] = xs[twl + quad * 4 + reg][r * 16 + l15];

  // ---- this wave's 8 n-iterations, 1-deep bundle prefetch ----
  #pragma unroll
  for (int j = 0; j < 8; ++j) {
    const int n = n0 + j;
    WFrag nxt = (j < 7) ? loadw(WBApk, bA, n + 1, l15, quad) : cur;

    const f32x4 z4 = {0.f, 0.f, 0.f, 0.f};
    f32x4 aac = z4;
    aac = __builtin_amdgcn_mfma_f32_16x16x32_bf16(a0, cur.a0f, aac, 0, 0, 0);
    aac = __builtin_amdgcn_mfma_f32_16x16x32_bf16(a1, cur.a1f, aac, 0, 0, 0);

    f32x4 ac0 = z4, ac1 = z4, ac2 = z4, ac3 = z4;
    ac0 = __builtin_amdgcn_mfma_f32_16x16x32_bf16(a0, cur.b00, ac0, 0, 0, 0);
    ac0 = __builtin_amdgcn_mfma_f32_16x16x32_bf16(a1, cur.b01, ac0, 0, 0, 0);
    ac1 = __builtin_amdgcn_mfma_f32_16x16x32_bf16(a0, cur.b10, ac1, 0, 0, 0);
    ac1 = __builtin_amdgcn_mfma_f32_16x16x32_bf16(a1, cur.b11, ac1, 0, 0, 0);
    ac2 = __builtin_amdgcn_mfma_f32_16x16x32_bf16(a0, cur.b20, ac2, 0, 0, 0);
    ac2 = __builtin_amdgcn_mfma_f32_16x16x32_bf16(a1, cur.b21, ac2, 0, 0, 0);
    ac3 = __builtin_amdgcn_mfma_f32_16x16x32_bf16(a0, cur.b30, ac3, 0, 0, 0);
    ac3 = __builtin_amdgcn_mfma_f32_16x16x32_bf16(a1, cur.b31, ac3, 0, 0, 0);

    // B epilogue
    const float bb0 = bBs[n * 64 +  0 + l15];
    const float bb1 = bBs[n * 64 + 16 + l15];
    const float bb2 = bBs[n * 64 + 32 + l15];
    const float bb3 = bBs[n * 64 + 48 + l15];
    float part[4];
    #pragma unroll
    for (int reg = 0; reg < 4; ++reg) {
      float s = fmaf(ac0[reg] + bb0, xv[0][reg], 0.f);
      s = fmaf(ac1[reg] + bb1, xv[1][reg], s);
      s = fmaf(ac2[reg] + bb2, xv[2][reg], s);
      s = fmaf(ac3[reg] + bb3, xv[3][reg], s);
      part[reg] = s;
    }
    #pragma unroll
    for (int off = 1; off < 16; off <<= 1) {
      #pragma unroll
      for (int reg = 0; reg < 4; ++reg)
        part[reg] += __shfl_xor(part[reg], off, 64);
    }
    if (l15 == 0) {
      #pragma unroll
      for (int reg = 0; reg < 4; ++reg)
        bxs[twl + quad * 4 + reg][n] = part[reg];
    }

    // A epilogue (LDS; flushed coalesced below)
    As[(twl + quad * 4 + 0) * AS_T + n * AS_I + l15] = f2bf(aac[0] + cur.ba);
    As[(twl + quad * 4 + 1) * AS_T + n * AS_I + l15] = f2bf(aac[1] + cur.ba);
    As[(twl + quad * 4 + 2) * AS_T + n * AS_I + l15] = f2bf(aac[2] + cur.ba);
    As[(twl + quad * 4 + 3) * AS_T + n * AS_I + l15] = f2bf(aac[3] + cur.ba);

    cur = nxt;
  }
  __syncthreads();

  // ---- flush A (32x256 bf16 = 1024 uint4) + Bx (128 float4) coalesced ----
  {
    uint4* Wg = (uint4*)(Wt_ws + (size_t)t0 * 256);
    #pragma unroll 1
    for (int z = 0; z < 4; ++z) {
      const int p4 = z * 256 + tid;
      const int f  = p4 * 8;
      const int t  = f >> 8, i = (f >> 4) & 15, k = f & 15;
      const unsigned short* sp = &As[t * AS_T + i * AS_I + k];
      uint2 lo = *(const uint2*)(sp);
      uint2 hi = *(const uint2*)(sp + 4);
      Wg[p4] = make_uint4(lo.x, lo.y, hi.x, hi.y);
    }
    if (tid < 128)
      ((float4*)(u_ws + (size_t)t0 * DS))[tid] = ((const float4*)&bxs[0][0])[tid];
  }
}

// ---------------------------------------------------------------------------
// G1B: scan phase (unchanged).
// ---------------------------------------------------------------------------
__global__ __launch_bounds__(256, 2) void g1b(
    unsigned short* __restrict__ Wt_ws, float* __restrict__ u_ws,
    float* __restrict__ P_ws, float* __restrict__ v_ws)
{
  __shared__ __align__(16) unsigned short As[64 * AS_T];    // 41472 B
  __shared__ __align__(16) float bxs[64][16];               //  4096 B
  __shared__ __align__(16) float us[4][16];                 //   256 B

  const int tid  = threadIdx.x;
  const int lane = tid & 63;
  const int l15  = lane & 15;
  const int quad = lane >> 4;
  const int w    = tid >> 6;             // 0..3
  const int t0   = blockIdx.x * 64;
  const int twl  = w * 16;

  // ---- stage A tile (2048 uint4) + Bx (256 float4); zero us ----
  {
    const uint4* Wg = (const uint4*)(Wt_ws + (size_t)t0 * 256);
    #pragma unroll 1
    for (int z = 0; z < 8; ++z) {
      const int p4 = z * 256 + tid;
      const int f  = p4 * 8;
      const int t  = f >> 8, i = (f >> 4) & 15, k = f & 15;
      uint4 v = Wg[p4];
      unsigned short* sp = &As[t * AS_T + i * AS_I + k];
      *(uint2*)(sp)     = make_uint2(v.x, v.y);
      *(uint2*)(sp + 4) = make_uint2(v.z, v.w);
    }
    ((float4*)bxs)[tid] = ((const float4*)(u_ws + (size_t)t0 * DS))[tid];
    if (tid < 64) us[tid >> 4][tid & 15] = 0.f;
  }
  __syncthreads();

  // ---- scan: wave w owns chunk blockIdx.x*4 + w (16 steps) ----
  {
    bf16x8 wb;          // W in B-operand layout: wb[j] = W[quad*8+j][l15]
    #pragma unroll
    for (int j = 0; j < 8; ++j) wb[j] = (__bf16)((quad * 8 + j == l15) ? 1.f : 0.f);
    f32x4 d = {0.f, 0.f, 0.f, 0.f};
    const int qq = quad & 1;

    // prefetch t=0's A-row
    const unsigned short* rpp = &As[twl * AS_T + l15 * AS_I];
    uint2 r0 = *(const uint2*)(rpp);
    uint2 r1 = *(const uint2*)(rpp + 4);
    uint2 r2 = *(const uint2*)(rpp + 8);
    uint2 r3 = *(const uint2*)(rpp + 12);

    #pragma unroll 1
    for (int t = 0; t < CHUNK; ++t) {
      const int tl = twl + t;

      // prefetch next step's A-row
      uint2 s0, s1, s2, s3;
      if (t < CHUNK - 1) {
        const unsigned short* rp = &As[(tl + 1) * AS_T + l15 * AS_I];
        s0 = *(const uint2*)(rp);
        s1 = *(const uint2*)(rp + 4);
        s2 = *(const uint2*)(rp + 8);
        s3 = *(const uint2*)(rp + 12);
      } else { s0 = r0; s1 = r1; s2 = r2; s3 = r3; }

      uint4 abits;
      if (quad == 0)      abits = make_uint4(r0.x, r0.y, r1.x, r1.y);
      else if (quad == 1) abits = make_uint4(r2.x, r2.y, r3.x, r3.y);
      else                abits = make_uint4(0u, 0u, 0u, 0u);
      bf16x8 af = *(bf16x8*)&abits;

      f32x4 z4 = {0.f, 0.f, 0.f, 0.f};
      d = __builtin_amdgcn_mfma_f32_16x16x32_bf16(af, wb, z4, 0, 0, 0);

      // u-chain: 4 partials
      float nu;
      {
        float4 U0 = *(const float4*)&us[w][0];
        float4 U1 = *(const float4*)&us[w][4];
        float4 U2 = *(const float4*)&us[w][8];
        float4 U3 = *(const float4*)&us[w][12];
        float n0 = bxs[tl][l15], n1 = 0.f, n2 = 0.f, n3 = 0.f;
        n0 = fmaf(bflo(r0.x), U0.x, n0); n0 = fmaf(bfhi(r0.x), U0.y, n0);
        n0 = fmaf(bflo(r0.y), U0.z, n0); n0 = fmaf(bfhi(r0.y), U0.w, n0);
        n1 = fmaf(bflo(r1.x), U1.x, n1); n1 = fmaf(bfhi(r1.x), U1.y, n1);
        n1 = fmaf(bflo(r1.y), U1.z, n1); n1 = fmaf(bfhi(r1.y), U1.w, n1);
        n2 = fmaf(bflo(r2.x), U2.x, n2); n2 = fmaf(bfhi(r2.x), U2.y, n2);
        n2 = fmaf(bflo(r2.y), U2.z, n2); n2 = fmaf(bfhi(r2.y), U2.w, n2);
        n3 = fmaf(bflo(r3.x), U3.x, n3); n3 = fmaf(bfhi(r3.x), U3.y, n3);
        n3 = fmaf(bflo(r3.y), U3.z, n3); n3 = fmaf(bfhi(r3.y), U3.w, n3);
        nu = (n0 + n1) + (n2 + n3);
      }

      bf16x8 nb;
      nb[0] = (__bf16)__shfl(d[0], (2 * qq + 0) * 16 + l15, 64);
      nb[1] = (__bf16)__shfl(d[1], (2 * qq + 0) * 16 + l15, 64);
      nb[2] = (__bf16)__shfl(d[2], (2 * qq + 0) * 16 + l15, 64);
      nb[3] = (__bf16)__shfl(d[3], (2 * qq + 0) * 16 + l15, 64);
      nb[4] = (__bf16)__shfl(d[0], (2 * qq + 1) * 16 + l15, 64);
      nb[5] = (__bf16)__shfl(d[1], (2 * qq + 1) * 16 + l15, 64);
      nb[6] = (__bf16)__shfl(d[2], (2 * qq + 1) * 16 + l15, 64);
      nb[7] = (__bf16)__shfl(d[3], (2 * qq + 1) * 16 + l15, 64);
      wb = nb;

      if (quad == 0) {
        us[w][l15] = nu;
        bxs[tl][l15] = nu;                 // u prefix in place
      }
      #pragma unroll
      for (int r = 0; r < 4; ++r)
        As[tl * AS_T + (quad * 4 + r) * AS_I + l15] = f2bf(d[r]);

      r0 = s0; r1 = s1; r2 = s2; r3 = s3;
    }

    const int chunk = blockIdx.x * 4 + w;
    #pragma unroll
    for (int r = 0; r < 4; ++r)
      P_ws[(size_t)chunk * 256 + (quad * 4 + r) * 16 + l15] = d[r];
    if (quad == 0) v_ws[(size_t)chunk * DS + l15] = us[w][l15];
  }
  __syncthreads();   // flush reads As/bxs across waves

  // ---- flush Wt (2048 uint4) + u (256 float4) coalesced, in place ----
  {
    uint4* Wg = (uint4*)(Wt_ws + (size_t)t0 * 256);
    #pragma unroll 1
    for (int z = 0; z < 8; ++z) {
      const int p4 = z * 256 + tid;
      const int f  = p4 * 8;
      const int t  = f >> 8, i = (f >> 4) & 15, k = f & 15;
      const unsigned short* sp = &As[t * AS_T + i * AS_I + k];
      uint2 lo = *(const uint2*)(sp);
      uint2 hi = *(const uint2*)(sp + 4);
      Wg[p4] = make_uint4(lo.x, lo.y, hi.x, hi.y);
    }
    ((float4*)(u_ws + (size_t)t0 * DS))[tid] = ((const float4*)&bxs[0][0])[tid];
  }
}

// ---------------------------------------------------------------------------
// K3F: fused k3a+k3b+k3c + L2 warm.  (unchanged, passing.)
// ---------------------------------------------------------------------------
__global__ __launch_bounds__(1024, 4) void k3f(
    const float* __restrict__ P_ws, const float* __restrict__ v_ws,
    float* __restrict__ hb_ws,
    const unsigned short* __restrict__ Wt_ws,
    const unsigned short* __restrict__ xb,
    const float* __restrict__ u_ws)
{
  __shared__ float Qs[16][256];    // 16 KB: folded supergroup transitions
  __shared__ float wsv[16][16];    //  1 KB: folded supergroup offsets
  __shared__ float hbgs[16][16];   //  1 KB: supergroup entry states

  const int tid = threadIdx.x;
  const int bx  = blockIdx.x;

  if (bx >= 8) {
    // ---- L2 warm of g2's inputs ----
    const uint4* wp = (const uint4*)(Wt_ws + (size_t)bx * 32 * 256);  // 16 KB
    uint4 a = wp[tid];
    const unsigned int* xp = (const unsigned int*)(xb + (size_t)bx * 32 * 64); // 4 KB
    unsigned int b = xp[tid];
    unsigned int c = 0;
    if (tid < 512) c = ((const unsigned int*)(u_ws + (size_t)bx * 32 * DS))[tid]; // 2 KB
    asm volatile("" :: "v"(a.x), "v"(b), "v"(c));
    return;
  }

  const int lane = tid & 63;
  const int l15  = lane & 15;
  const int quad = lane >> 4;
  const int wv   = tid >> 6;       // 0..15
  const int qq   = quad & 1;

  // ======== phase A: fold 16 chunks of supergroup s = bx*16 + wv ========
  {
    const int s = bx * 16 + wv;
    if (lane < 16) wsv[wv][lane] = 0.f;
    bf16x8 wb;
    #pragma unroll
    for (int j = 0; j < 8; ++j) wb[j] = (__bf16)((quad * 8 + j == l15) ? 1.f : 0.f);
    f32x4 d = {0.f, 0.f, 0.f, 0.f};

    float4 p0 = {0.f,0.f,0.f,0.f}, p1 = {0.f,0.f,0.f,0.f};
    float nv;
    {
      const int chunk = s * SG;
      if (quad < 2) {
        const float4* pr = (const float4*)(P_ws + (size_t)chunk * 256 + l15 * 16 + quad * 8);
        p0 = pr[0]; p1 = pr[1];
      }
      nv = v_ws[(size_t)chunk * DS + l15];
    }

    #pragma unroll 1
    for (int t = 0; t < SG; ++t) {
      float4 q0 = {0.f,0.f,0.f,0.f}, q1 = {0.f,0.f,0.f,0.f};
      float nv2 = 0.f;
      if (t < SG - 1) {
        const int chunk = s * SG + t + 1;
        if (quad < 2) {
          const float4* pr = (const float4*)(P_ws + (size_t)chunk * 256 + l15 * 16 + quad * 8);
          q0 = pr[0]; q1 = pr[1];
        }
        nv2 = v_ws[(size_t)chunk * DS + l15];
      }

      bf16x8 af;
      af[0] = (__bf16)p0.x; af[1] = (__bf16)p0.y; af[2] = (__bf16)p0.z; af[3] = (__bf16)p0.w;
      af[4] = (__bf16)p1.x; af[5] = (__bf16)p1.y; af[6] = (__bf16)p1.z; af[7] = (__bf16)p1.w;

      f32x4 z4 = {0.f, 0.f, 0.f, 0.f};
      d = __builtin_amdgcn_mfma_f32_16x16x32_bf16(af, wb, z4, 0, 0, 0);

      float part = 0.f;
      if (quad < 2) {
        const float* wrow = &wsv[wv][quad * 8];
        part = p0.x*wrow[0] + p0.y*wrow[1] + p0.z*wrow[2] + p0.w*wrow[3]
             + p1.x*wrow[4] + p1.y*wrow[5] + p1.z*wrow[6] + p1.w*wrow[7];
      }
      part += __shfl_xor(part, 16, 64);

      bf16x8 nb;
      nb[0] = (__bf16)__shfl(d[0], (2 * qq + 0) * 16 + l15, 64);
      nb[1] = (__bf16)__shfl(d[1], (2 * qq + 0) * 16 + l15, 64);
      nb[2] = (__bf16)__shfl(d[2], (2 * qq + 0) * 16 + l15, 64);
      nb[3] = (__bf16)__shfl(d[3], (2 * qq + 0) * 16 + l15, 64);
      nb[4] = (__bf16)__shfl(d[0], (2 * qq + 1) * 16 + l15, 64);
      nb[5] = (__bf16)__shfl(d[1], (2 * qq + 1) * 16 + l15, 64);
      nb[6] = (__bf16)__shfl(d[2], (2 * qq + 1) * 16 + l15, 64);
      nb[7] = (__bf16)__shfl(d[3], (2 * qq + 1) * 16 + l15, 64);
      wb = nb;

      if (quad == 0) wsv[wv][l15] = part + nv;

      p0 = q0; p1 = q1; nv = nv2;
    }

    #pragma unroll
    for (int r = 0; r < 4; ++r)
      Qs[wv][(quad * 4 + r) * 16 + l15] = d[r];
  }
  __syncthreads();

  // ======== phase B: scan 16 supergroups of this batch (16 lanes) ========
  if (tid < 16) {
    const int r = tid;
    float h = 0.f;
    #pragma unroll 1
    for (int g = 0; g < 16; ++g) {
      hbgs[g][r] = h;
      const float4* Pr = (const float4*)&Qs[g][r * 16];
      float4 c0 = Pr[0], c1 = Pr[1], c2 = Pr[2], c3 = Pr[3];
      const float vc = wsv[g][r];
      float a0 = c0.x*__shfl(h, 0,16) + c0.y*__shfl(h, 1,16) + c0.z*__shfl(h, 2,16) + c0.w*__shfl(h, 3,16);
      float a1 = c1.x*__shfl(h, 4,16) + c1.y*__shfl(h, 5,16) + c1.z*__shfl(h, 6,16) + c1.w*__shfl(h, 7,16);
      float a2 = c2.x*__shfl(h, 8,16) + c2.y*__shfl(h, 9,16) + c2.z*__shfl(h,10,16) + c2.w*__shfl(h,11,16);
      float a3 = c3.x*__shfl(h,12,16) + c3.y*__shfl(h,13,16) + c3.z*__shfl(h,14,16) + c3.w*__shfl(h,15,16);
      h = vc + ((a0 + a1) + (a2 + a3));
    }
  }
  __syncthreads();

  // ======== phase C: replay chunks of supergroup g (256 threads) ========
  if (tid < 256) {
    const int g = tid >> 4;
    const int r = tid & 15;
    const int s = bx * 16 + g;
    float h = hbgs[g][r];

    float4 c0, c1, c2, c3; float vc;
    {
      const int chunk = s * SG;
      const float4* Pr = (const float4*)&P_ws[(size_t)chunk * 256 + r * 16];
      c0 = Pr[0]; c1 = Pr[1]; c2 = Pr[2]; c3 = Pr[3];
      vc = v_ws[(size_t)chunk * DS + r];
    }

    #pragma unroll 1
    for (int t = 0; t < SG; ++t) {
      const int chunk = s * SG + t;
      float4 d0, d1, d2, d3; float vc2;
      if (t < SG - 1) {
        const float4* Pr = (const float4*)&P_ws[(size_t)(chunk + 1) * 256 + r * 16];
        d0 = Pr[0]; d1 = Pr[1]; d2 = Pr[2]; d3 = Pr[3];
        vc2 = v_ws[(size_t)(chunk + 1) * DS + r];
      } else { d0 = c0; d1 = c1; d2 = c2; d3 = c3; vc2 = vc; }

      hb_ws[(size_t)chunk * DS + r] = h;
      float a0 = c0.x*__shfl(h, 0,16) + c0.y*__shfl(h, 1,16) + c0.z*__shfl(h, 2,16) + c0.w*__shfl(h, 3,16);
      float a1 = c1.x*__shfl(h, 4,16) + c1.y*__shfl(h, 5,16) + c1.z*__shfl(h, 6,16) + c1.w*__shfl(h, 7,16);
      float a2 = c2.x*__shfl(h, 8,16) + c2.y*__shfl(h, 9,16) + c2.z*__shfl(h,10,16) + c2.w*__shfl(h,11,16);
      float a3 = c3.x*__shfl(h,12,16) + c3.y*__shfl(h,13,16) + c3.z*__shfl(h,14,16) + c3.w*__shfl(h,15,16);
      h = vc + ((a0 + a1) + (a2 + a3));

      c0 = d0; c1 = d1; c2 = d2; c3 = d3; vc = vc2;
    }
  }
}

// ---------------------------------------------------------------------------
// G2 v3: per block 16 t (= exactly ONE chunk), 256 thr (4 waves), wave w
// owns r-column w.  Grid 2048 blocks = 8 blocks/CU = 8 waves/SIMD (was 4).
// Phase 1 is exactly 1 cell/thread -> ALL 256 threads' Wt/u/hb loads issue
// in one batch (8 KB/block in flight vs ~100 B/wave before): fixes the
// measured MLP bound (600 GB/s effective fetch, dur == FETCH/600GB/s).
// ~48 live VGPRs peak, fits the 64-VGPR cap of launch_bounds(256,8).
// ---------------------------------------------------------------------------
__global__ __launch_bounds__(256, 8) void g2(
    const unsigned short* __restrict__ xb, const unsigned short* __restrict__ WCpk,
    const float* __restrict__ bC, const unsigned short* __restrict__ Wt_ws,
    const float* __restrict__ u_ws, const float* __restrict__ hb_ws,
    float* __restrict__ out)
{
  __shared__ float hsh[16][17];
  __shared__ float bCs[1024];
  const int tid  = threadIdx.x;
  const int lane = tid & 63;
  const int l15  = lane & 15;
  const int quad = lane >> 4;
  const int w    = tid >> 6;        // 0..3 = r-column block
  const int t0   = blockIdx.x * 16; // one chunk per block
  const int rc   = w;

  ((float4*)bCs)[tid] = ((const float4*)bC)[tid];

  // A-frag loads (consumed in phase 2) — issued early
  const bf16x8* xvp = (const bf16x8*)(xb + (size_t)(t0 + l15) * 64);
  bf16x8 a0 = xvp[quad];
  bf16x8 a1 = xvp[quad + 4];

  // ---- phase 1: 1 cell/thread, all loads batch-issued ----
  const int tl = tid >> 4, i = tid & 15;
  const int t  = t0 + tl;
  const uint4* wr = (const uint4*)(Wt_ws + (size_t)t * 256 + i * 16);
  uint4 wa = wr[0], wbv = wr[1];
  const float4* hp = (const float4*)(hb_ws + (size_t)blockIdx.x * DS); // chunk = blockIdx
  float4 h0 = hp[0], h1 = hp[1], h2 = hp[2], h3 = hp[3];
  float uu = u_ws[(size_t)t * DS + i];
  {
    float p0 = uu, p1 = 0.f, p2 = 0.f, p3 = 0.f;
    p0 = fmaf(bflo(wa.x),  h0.x, p0); p0 = fmaf(bfhi(wa.x),  h0.y, p0);
    p0 = fmaf(bflo(wa.y),  h0.z, p0); p0 = fmaf(bfhi(wa.y),  h0.w, p0);
    p1 = fmaf(bflo(wa.z),  h1.x, p1); p1 = fmaf(bfhi(wa.z),  h1.y, p1);
    p1 = fmaf(bflo(wa.w),  h1.z, p1); p1 = fmaf(bfhi(wa.w),  h1.w, p1);
    p2 = fmaf(bflo(wbv.x), h2.x, p2); p2 = fmaf(bfhi(wbv.x), h2.y, p2);
    p2 = fmaf(bflo(wbv.y), h2.z, p2); p2 = fmaf(bfhi(wbv.y), h2.w, p2);
    p3 = fmaf(bflo(wbv.z), h3.x, p3); p3 = fmaf(bfhi(wbv.z), h3.y, p3);
    p3 = fmaf(bflo(wbv.w), h3.z, p3); p3 = fmaf(bfhi(wbv.w), h3.w, p3);
    hsh[tl][i] = (p0 + p1) + (p2 + p3);
  }
  __syncthreads();

  // ---- phase 2: output projection, 1 r-column/wave, 1-deep prefetch ----
  f32x4 o0 = {0.f, 0.f, 0.f, 0.f};

  const bf16x8* cp = (const bf16x8*)(WCpk + (size_t)((0 * 4 + rc) * 64 + l15 * 4 + quad) * 16);
  bf16x8 c00 = cp[0], c01 = cp[1];
  #pragma unroll
  for (int n = 0; n < 16; ++n) {
    bf16x8 n00 = c00, n01 = c01;
    if (n < 15) {
      const bf16x8* np = (const bf16x8*)(WCpk + (size_t)(((n + 1) * 4 + rc) * 64 + l15 * 4 + quad) * 16);
      n00 = np[0]; n01 = np[1];
    }

    f32x4 ac0 = {0.f, 0.f, 0.f, 0.f};
    ac0 = __builtin_amdgcn_mfma_f32_16x16x32_bf16(a0, c00, ac0, 0, 0, 0);
    ac0 = __builtin_amdgcn_mfma_f32_16x16x32_bf16(a1, c01, ac0, 0, 0, 0);

    float hn[4];
    #pragma unroll
    for (int reg = 0; reg < 4; ++reg) hn[reg] = hsh[quad * 4 + reg][n];

    const float bc0 = bCs[n * 64 + rc * 16 + l15];
    #pragma unroll
    for (int reg = 0; reg < 4; ++reg)
      o0[reg] = fmaf(ac0[reg] + bc0, hn[reg], o0[reg]);

    c00 = n00; c01 = n01;
  }

  #pragma unroll
  for (int reg = 0; reg < 4; ++reg)
    out[(size_t)(t0 + quad * 4 + reg) * DM + rc * 16 + l15] = o0[reg];
}

// ---------------------------------------------------------------------------
extern "C" void kernel_launch(void* const* d_in, const int* in_sizes, int n_in,
                              void* d_out, int out_size, void* d_ws, size_t ws_size,
                              hipStream_t stream) {
  const float* x  = (const float*)d_in[0];
  const float* WA = (const float*)d_in[1];
  const float* bA = (const float*)d_in[2];
  const float* WB = (const float*)d_in[3];
  const float* bB = (const float*)d_in[4];
  const float* WC = (const float*)d_in[5];
  const float* bC = (const float*)d_in[6];
  float* out = (float*)d_out;

  float* ws     = (float*)d_ws;
  float* P_ws   = ws;                               // NCHT*256 (2 MB)
  float* v_ws   = P_ws   + (size_t)NCHT * 256;      // NCHT*16
  float* u_ws   = v_ws   + (size_t)NCHT * DS;       // BS*16
  float* Q_ws   = u_ws   + (size_t)BS * DS;         // NSG*256 (unused)
  float* w_ws   = Q_ws   + (size_t)NSG * 256;       // NSG*16  (unused)
  float* hbg_ws = w_ws   + (size_t)NSG * DS;        // NSG*16  (unused)
  float* hb_ws  = hbg_ws + (size_t)NSG * DS;        // NCHT*16
  unsigned short* xb    = (unsigned short*)(hb_ws + (size_t)NCHT * DS);
  unsigned short* WBApk = xb    + (size_t)BS * 64;  // 81920 ushorts (packed WB+WA)
  unsigned short* WCpk  = WBApk + 81920;            // 65536 ushorts (packed WC)
  unsigned short* Wt_ws = WCpk  + 65536;            // BS*256 (16.8 MB)

  k0_castw<<<576,      256, 0, stream>>>(WA, WB, WC, WBApk, WCpk);
  g1a     <<<BS / 32,  256, 0, stream>>>(x, WBApk, bB, bA, xb, Wt_ws, u_ws);
  g1b     <<<BS / 64,  256, 0, stream>>>(Wt_ws, u_ws, P_ws, v_ws);
  k3f     <<<1024,    1024, 0, stream>>>(P_ws, v_ws, hb_ws, Wt_ws, xb, u_ws);
  g2      <<<BS / 16,  256, 0, stream>>>(xb, WCpk, bC, Wt_ws, u_ws, hb_ws, out);
}

// Round 10
// 175.014 us; speedup vs baseline: 1.1307x; 1.1307x over previous
//
#include <hip/hip_runtime.h>

// Problem constants (B=8, S=4096, D=64, ds=16)
#define BATCH   8
#define SEQ     4096
#define DM      64
#define DS      16
#define BS      (BATCH*SEQ)      // 32768 timesteps
#define CHUNK   16               // scan chunk length
#define NCHT    (BS/CHUNK)       // 2048 chunks total (256 per batch)
#define SG      16               // chunks per supergroup
#define NSG     (NCHT/SG)        // 128 supergroups (16 per batch)

typedef __attribute__((ext_vector_type(8))) __bf16 bf16x8;
typedef __attribute__((ext_vector_type(4))) float  f32x4;

__device__ __forceinline__ unsigned short f2bf(float f) {
  unsigned int u = __float_as_uint(f);
  u += 0x7fffu + ((u >> 16) & 1u);          // RNE (finite values)
  return (unsigned short)(u >> 16);
}
__device__ __forceinline__ float bflo(unsigned int u) { return __uint_as_float(u << 16); }
__device__ __forceinline__ float bfhi(unsigned int u) { return __uint_as_float(u & 0xffff0000u); }

// LDS A-tile strides (ushorts): per-i 20 (40B), per-t 324 (648B)
#define AS_I 20
#define AS_T 324

// ---------------------------------------------------------------------------
// K0: cast + PACK weights (unchanged).
// ---------------------------------------------------------------------------
__global__ __launch_bounds__(256) void k0_castw(
    const float* __restrict__ WA, const float* __restrict__ WB,
    const float* __restrict__ WC,
    unsigned short* __restrict__ WBApk, unsigned short* __restrict__ WCpk)
{
  const int o = blockIdx.x * 256 + threadIdx.x;
  if (o < 81920) {
    int idx = o;
    const int e = idx & 7;    idx >>= 3;
    const int f = idx % 10;   idx /= 10;
    const int quad = idx & 3; idx >>= 2;
    const int l15 = idx & 15; idx >>= 4;
    const int n = idx;                      // 0..15
    float src;
    if (f < 8) {
      const int r = f >> 1, h = f & 1;
      src = WB[(h * 32 + quad * 8 + e) * 1024 + (n * 4 + r) * 16 + l15];
    } else {
      const int h = f - 8;
      src = WA[(h * 32 + quad * 8 + e) * 256 + n * 16 + l15];
    }
    WBApk[o] = f2bf(src);
  } else {
    const int p = o - 81920;                // 0..65535
    const int e = p & 7;
    const int h = (p >> 3) & 1;
    const int quad = (p >> 4) & 3;
    const int l15 = (p >> 6) & 15;
    const int nr = p >> 10;                 // n*4+rc, 0..63
    WCpk[p] = f2bf(WC[(h * 32 + quad * 8 + e) * 1024 + nr * 16 + l15]);
  }
}

// Weight-fragment bundle for one n-iteration of the merged B/A loop.
struct WFrag {
  bf16x8 b00, b01, b10, b11, b20, b21, b30, b31;  // WB frags, r=0..3 x 2 halves
  bf16x8 a0f, a1f;                                 // WA frags
  float  ba;                                       // bA bias
};

__device__ __forceinline__ WFrag loadw(
    const unsigned short* __restrict__ WBApk,
    const float* __restrict__ bA, int n, int l15, int quad)
{
  WFrag f;
  const bf16x8* fp = (const bf16x8*)(WBApk + (size_t)((n * 16 + l15) * 4 + quad) * 80);
  f.b00 = fp[0]; f.b01 = fp[1];
  f.b10 = fp[2]; f.b11 = fp[3];
  f.b20 = fp[4]; f.b21 = fp[5];
  f.b30 = fp[6]; f.b31 = fp[7];
  f.a0f = fp[8]; f.a1f = fp[9];
  f.ba  = bA[n * 16 + l15];
  return f;
}

// ---------------------------------------------------------------------------
// G1: monolithic GEMM+scan (REVERTED to the r6 version, proven 50 µs / pass).
// The r7 g1a/g1b split bought the g2 diagnosis but cost a full Wt round-trip
// (+33.6 MB) + one launch; paying that back now.
// ---------------------------------------------------------------------------
__global__ __launch_bounds__(256, 2) void g1(
    const float* __restrict__ x, const unsigned short* __restrict__ WBApk,
    const float* __restrict__ bB,
    const float* __restrict__ bA, unsigned short* __restrict__ xb,
    unsigned short* __restrict__ Wt_ws, float* __restrict__ u_ws,
    float* __restrict__ P_ws, float* __restrict__ v_ws)
{
  __shared__ __align__(16) float xs[64][68];                // 17408 B
  __shared__ __align__(16) float bBs[1024];                 //  4096 B
  __shared__ __align__(16) unsigned short As[64 * AS_T];    // 41472 B
  __shared__ __align__(16) float bxs[64][16];               //  4096 B
  __shared__ __align__(16) float us[4][16];                 //   256 B

  const int tid  = threadIdx.x;
  const int lane = tid & 63;
  const int l15  = lane & 15;
  const int quad = lane >> 4;
  const int w    = tid >> 6;             // 0..3
  const int t0   = blockIdx.x * 64;
  const int twl  = w * 16;

  { // stage fp32 x tile (64x64 = 1024 float4) + bB (256 float4); zero us
    const float4* xg = (const float4*)(x + (size_t)t0 * DM);
    #pragma unroll
    for (int i = 0; i < 4; ++i) {
      const int f4 = tid + 256 * i;
      ((float4*)&xs[f4 >> 4][0])[f4 & 15] = xg[f4];
    }
    ((float4*)bBs)[tid] = ((const float4*)bB)[tid];
    if (tid < 64) us[tid >> 4][tid & 15] = 0.f;
  }
  __syncthreads();

  // issue first weight-fragment bundle so it overlaps the frag build below
  WFrag cur = loadw(WBApk, bA, 0, l15, quad);

  // ---- build A-operand frags from LDS; store to xb for g2 ----
  bf16x8 a0, a1;
  {
    const int row = twl + l15;
    union { bf16x8 v; ushort4 s[2]; } ua, ub;
    float4 p0 = *(const float4*)&xs[row][quad * 8];
    float4 p1 = *(const float4*)&xs[row][quad * 8 + 4];
    float4 p2 = *(const float4*)&xs[row][32 + quad * 8];
    float4 p3 = *(const float4*)&xs[row][32 + quad * 8 + 4];
    ua.s[0] = (ushort4){f2bf(p0.x), f2bf(p0.y), f2bf(p0.z), f2bf(p0.w)};
    ua.s[1] = (ushort4){f2bf(p1.x), f2bf(p1.y), f2bf(p1.z), f2bf(p1.w)};
    ub.s[0] = (ushort4){f2bf(p2.x), f2bf(p2.y), f2bf(p2.z), f2bf(p2.w)};
    ub.s[1] = (ushort4){f2bf(p3.x), f2bf(p3.y), f2bf(p3.z), f2bf(p3.w)};
    a0 = ua.v; a1 = ub.v;
    unsigned short* xp = xb + (size_t)(t0 + row) * 64 + quad * 8;
    *(bf16x8*)xp        = a0;
    *(bf16x8*)(xp + 32) = a1;
  }

  // hoist B-epilogue x values (constant across n): xv[r][reg]
  float xv[4][4];
  #pragma unroll
  for (int r = 0; r < 4; ++r)
    #pragma unroll
    for (int reg = 0; reg < 4; ++reg)
      xv[r][reg] = xs[twl + quad * 4 + reg][r * 16 + l15];

  // ---- merged B+A phase: per n, prefetch n+1's weights, 10 MFMAs ----
  #pragma unroll
  for (int n = 0; n < 16; ++n) {
    WFrag nxt = (n < 15) ? loadw(WBApk, bA, n + 1, l15, quad) : cur;

    const f32x4 z4 = {0.f, 0.f, 0.f, 0.f};
    f32x4 aac = z4;
    aac = __builtin_amdgcn_mfma_f32_16x16x32_bf16(a0, cur.a0f, aac, 0, 0, 0);
    aac = __builtin_amdgcn_mfma_f32_16x16x32_bf16(a1, cur.a1f, aac, 0, 0, 0);

    f32x4 ac0 = z4, ac1 = z4, ac2 = z4, ac3 = z4;
    ac0 = __builtin_amdgcn_mfma_f32_16x16x32_bf16(a0, cur.b00, ac0, 0, 0, 0);
    ac0 = __builtin_amdgcn_mfma_f32_16x16x32_bf16(a1, cur.b01, ac0, 0, 0, 0);
    ac1 = __builtin_amdgcn_mfma_f32_16x16x32_bf16(a0, cur.b10, ac1, 0, 0, 0);
    ac1 = __builtin_amdgcn_mfma_f32_16x16x32_bf16(a1, cur.b11, ac1, 0, 0, 0);
    ac2 = __builtin_amdgcn_mfma_f32_16x16x32_bf16(a0, cur.b20, ac2, 0, 0, 0);
    ac2 = __builtin_amdgcn_mfma_f32_16x16x32_bf16(a1, cur.b21, ac2, 0, 0, 0);
    ac3 = __builtin_amdgcn_mfma_f32_16x16x32_bf16(a0, cur.b30, ac3, 0, 0, 0);
    ac3 = __builtin_amdgcn_mfma_f32_16x16x32_bf16(a1, cur.b31, ac3, 0, 0, 0);

    // B epilogue
    const float bb0 = bBs[n * 64 +  0 + l15];
    const float bb1 = bBs[n * 64 + 16 + l15];
    const float bb2 = bBs[n * 64 + 32 + l15];
    const float bb3 = bBs[n * 64 + 48 + l15];
    float part[4];
    #pragma unroll
    for (int reg = 0; reg < 4; ++reg) {
      float s = fmaf(ac0[reg] + bb0, xv[0][reg], 0.f);
      s = fmaf(ac1[reg] + bb1, xv[1][reg], s);
      s = fmaf(ac2[reg] + bb2, xv[2][reg], s);
      s = fmaf(ac3[reg] + bb3, xv[3][reg], s);
      part[reg] = s;
    }
    #pragma unroll
    for (int off = 1; off < 16; off <<= 1) {
      #pragma unroll
      for (int reg = 0; reg < 4; ++reg)
        part[reg] += __shfl_xor(part[reg], off, 64);
    }
    if (l15 == 0) {
      #pragma unroll
      for (int reg = 0; reg < 4; ++reg)
        bxs[twl + quad * 4 + reg][n] = part[reg];
    }

    // A epilogue
    As[(twl + quad * 4 + 0) * AS_T + n * AS_I + l15] = f2bf(aac[0] + cur.ba);
    As[(twl + quad * 4 + 1) * AS_T + n * AS_I + l15] = f2bf(aac[1] + cur.ba);
    As[(twl + quad * 4 + 2) * AS_T + n * AS_I + l15] = f2bf(aac[2] + cur.ba);
    As[(twl + quad * 4 + 3) * AS_T + n * AS_I + l15] = f2bf(aac[3] + cur.ba);

    cur = nxt;
  }
  // Each wave's As/bxs/us rows are its own -> no barrier before scan.

  // ---- scan: wave w owns chunk blockIdx.x*4 + w (16 steps) ----
  {
    bf16x8 wb;          // W in B-operand layout: wb[j] = W[quad*8+j][l15]
    #pragma unroll
    for (int j = 0; j < 8; ++j) wb[j] = (__bf16)((quad * 8 + j == l15) ? 1.f : 0.f);
    f32x4 d = {0.f, 0.f, 0.f, 0.f};
    const int qq = quad & 1;

    // prefetch t=0's A-row
    const unsigned short* rpp = &As[twl * AS_T + l15 * AS_I];
    uint2 r0 = *(const uint2*)(rpp);
    uint2 r1 = *(const uint2*)(rpp + 4);
    uint2 r2 = *(const uint2*)(rpp + 8);
    uint2 r3 = *(const uint2*)(rpp + 12);

    #pragma unroll 1
    for (int t = 0; t < CHUNK; ++t) {
      const int tl = twl + t;

      // prefetch next step's A-row (timestep tl+1 untouched by writebacks)
      uint2 s0, s1, s2, s3;
      if (t < CHUNK - 1) {
        const unsigned short* rp = &As[(tl + 1) * AS_T + l15 * AS_I];
        s0 = *(const uint2*)(rp);
        s1 = *(const uint2*)(rp + 4);
        s2 = *(const uint2*)(rp + 8);
        s3 = *(const uint2*)(rp + 12);
      } else { s0 = r0; s1 = r1; s2 = r2; s3 = r3; }

      uint4 abits;
      if (quad == 0)      abits = make_uint4(r0.x, r0.y, r1.x, r1.y);
      else if (quad == 1) abits = make_uint4(r2.x, r2.y, r3.x, r3.y);
      else                abits = make_uint4(0u, 0u, 0u, 0u);
      bf16x8 af = *(bf16x8*)&abits;

      f32x4 z4 = {0.f, 0.f, 0.f, 0.f};
      d = __builtin_amdgcn_mfma_f32_16x16x32_bf16(af, wb, z4, 0, 0, 0);

      // u-chain: 4 partials
      float nu;
      {
        float4 U0 = *(const float4*)&us[w][0];
        float4 U1 = *(const float4*)&us[w][4];
        float4 U2 = *(const float4*)&us[w][8];
        float4 U3 = *(const float4*)&us[w][12];
        float n0 = bxs[tl][l15], n1 = 0.f, n2 = 0.f, n3 = 0.f;
        n0 = fmaf(bflo(r0.x), U0.x, n0); n0 = fmaf(bfhi(r0.x), U0.y, n0);
        n0 = fmaf(bflo(r0.y), U0.z, n0); n0 = fmaf(bfhi(r0.y), U0.w, n0);
        n1 = fmaf(bflo(r1.x), U1.x, n1); n1 = fmaf(bfhi(r1.x), U1.y, n1);
        n1 = fmaf(bflo(r1.y), U1.z, n1); n1 = fmaf(bfhi(r1.y), U1.w, n1);
        n2 = fmaf(bflo(r2.x), U2.x, n2); n2 = fmaf(bfhi(r2.x), U2.y, n2);
        n2 = fmaf(bflo(r2.y), U2.z, n2); n2 = fmaf(bfhi(r2.y), U2.w, n2);
        n3 = fmaf(bflo(r3.x), U3.x, n3); n3 = fmaf(bfhi(r3.x), U3.y, n3);
        n3 = fmaf(bflo(r3.y), U3.z, n3); n3 = fmaf(bfhi(r3.y), U3.w, n3);
        nu = (n0 + n1) + (n2 + n3);
      }

      bf16x8 nb;
      nb[0] = (__bf16)__shfl(d[0], (2 * qq + 0) * 16 + l15, 64);
      nb[1] = (__bf16)__shfl(d[1], (2 * qq + 0) * 16 + l15, 64);
      nb[2] = (__bf16)__shfl(d[2], (2 * qq + 0) * 16 + l15, 64);
      nb[3] = (__bf16)__shfl(d[3], (2 * qq + 0) * 16 + l15, 64);
      nb[4] = (__bf16)__shfl(d[0], (2 * qq + 1) * 16 + l15, 64);
      nb[5] = (__bf16)__shfl(d[1], (2 * qq + 1) * 16 + l15, 64);
      nb[6] = (__bf16)__shfl(d[2], (2 * qq + 1) * 16 + l15, 64);
      nb[7] = (__bf16)__shfl(d[3], (2 * qq + 1) * 16 + l15, 64);
      wb = nb;

      if (quad == 0) {
        us[w][l15] = nu;
        bxs[tl][l15] = nu;                 // u prefix in place
      }
      #pragma unroll
      for (int r = 0; r < 4; ++r)
        As[tl * AS_T + (quad * 4 + r) * AS_I + l15] = f2bf(d[r]);

      r0 = s0; r1 = s1; r2 = s2; r3 = s3;
    }

    const int chunk = blockIdx.x * 4 + w;
    #pragma unroll
    for (int r = 0; r < 4; ++r)
      P_ws[(size_t)chunk * 256 + (quad * 4 + r) * 16 + l15] = d[r];
    if (quad == 0) v_ws[(size_t)chunk * DS + l15] = us[w][l15];
  }
  __syncthreads();   // flush reads As/bxs across waves

  // ---- flush Wt (64x256 bf16 = 2048 uint4) + u (256 float4) coalesced ----
  {
    uint4* Wg = (uint4*)(Wt_ws + (size_t)t0 * 256);
    #pragma unroll 1
    for (int z = 0; z < 8; ++z) {
      const int p4 = z * 256 + tid;
      const int f  = p4 * 8;
      const int t  = f >> 8, i = (f >> 4) & 15, k = f & 15;
      const unsigned short* sp = &As[t * AS_T + i * AS_I + k];
      uint2 lo = *(const uint2*)(sp);
      uint2 hi = *(const uint2*)(sp + 4);
      Wg[p4] = make_uint4(lo.x, lo.y, hi.x, hi.y);
    }
    ((float4*)(u_ws + (size_t)t0 * DS))[tid] = ((const float4*)&bxs[0][0])[tid];
  }
}

// ---------------------------------------------------------------------------
// K3F: fused k3a+k3b+k3c + L2 warm.  (unchanged, passing.)
// ---------------------------------------------------------------------------
__global__ __launch_bounds__(1024, 4) void k3f(
    const float* __restrict__ P_ws, const float* __restrict__ v_ws,
    float* __restrict__ hb_ws,
    const unsigned short* __restrict__ Wt_ws,
    const unsigned short* __restrict__ xb,
    const float* __restrict__ u_ws)
{
  __shared__ float Qs[16][256];    // 16 KB: folded supergroup transitions
  __shared__ float wsv[16][16];    //  1 KB: folded supergroup offsets
  __shared__ float hbgs[16][16];   //  1 KB: supergroup entry states

  const int tid = threadIdx.x;
  const int bx  = blockIdx.x;

  if (bx >= 8) {
    // ---- L2 warm of g2's inputs ----
    const uint4* wp = (const uint4*)(Wt_ws + (size_t)bx * 32 * 256);  // 16 KB
    uint4 a = wp[tid];
    const unsigned int* xp = (const unsigned int*)(xb + (size_t)bx * 32 * 64); // 4 KB
    unsigned int b = xp[tid];
    unsigned int c = 0;
    if (tid < 512) c = ((const unsigned int*)(u_ws + (size_t)bx * 32 * DS))[tid]; // 2 KB
    asm volatile("" :: "v"(a.x), "v"(b), "v"(c));
    return;
  }

  const int lane = tid & 63;
  const int l15  = lane & 15;
  const int quad = lane >> 4;
  const int wv   = tid >> 6;       // 0..15
  const int qq   = quad & 1;

  // ======== phase A: fold 16 chunks of supergroup s = bx*16 + wv ========
  {
    const int s = bx * 16 + wv;
    if (lane < 16) wsv[wv][lane] = 0.f;
    bf16x8 wb;
    #pragma unroll
    for (int j = 0; j < 8; ++j) wb[j] = (__bf16)((quad * 8 + j == l15) ? 1.f : 0.f);
    f32x4 d = {0.f, 0.f, 0.f, 0.f};

    float4 p0 = {0.f,0.f,0.f,0.f}, p1 = {0.f,0.f,0.f,0.f};
    float nv;
    {
      const int chunk = s * SG;
      if (quad < 2) {
        const float4* pr = (const float4*)(P_ws + (size_t)chunk * 256 + l15 * 16 + quad * 8);
        p0 = pr[0]; p1 = pr[1];
      }
      nv = v_ws[(size_t)chunk * DS + l15];
    }

    #pragma unroll 1
    for (int t = 0; t < SG; ++t) {
      float4 q0 = {0.f,0.f,0.f,0.f}, q1 = {0.f,0.f,0.f,0.f};
      float nv2 = 0.f;
      if (t < SG - 1) {
        const int chunk = s * SG + t + 1;
        if (quad < 2) {
          const float4* pr = (const float4*)(P_ws + (size_t)chunk * 256 + l15 * 16 + quad * 8);
          q0 = pr[0]; q1 = pr[1];
        }
        nv2 = v_ws[(size_t)chunk * DS + l15];
      }

      bf16x8 af;
      af[0] = (__bf16)p0.x; af[1] = (__bf16)p0.y; af[2] = (__bf16)p0.z; af[3] = (__bf16)p0.w;
      af[4] = (__bf16)p1.x; af[5] = (__bf16)p1.y; af[6] = (__bf16)p1.z; af[7] = (__bf16)p1.w;

      f32x4 z4 = {0.f, 0.f, 0.f, 0.f};
      d = __builtin_amdgcn_mfma_f32_16x16x32_bf16(af, wb, z4, 0, 0, 0);

      float part = 0.f;
      if (quad < 2) {
        const float* wrow = &wsv[wv][quad * 8];
        part = p0.x*wrow[0] + p0.y*wrow[1] + p0.z*wrow[2] + p0.w*wrow[3]
             + p1.x*wrow[4] + p1.y*wrow[5] + p1.z*wrow[6] + p1.w*wrow[7];
      }
      part += __shfl_xor(part, 16, 64);

      bf16x8 nb;
      nb[0] = (__bf16)__shfl(d[0], (2 * qq + 0) * 16 + l15, 64);
      nb[1] = (__bf16)__shfl(d[1], (2 * qq + 0) * 16 + l15, 64);
      nb[2] = (__bf16)__shfl(d[2], (2 * qq + 0) * 16 + l15, 64);
      nb[3] = (__bf16)__shfl(d[3], (2 * qq + 0) * 16 + l15, 64);
      nb[4] = (__bf16)__shfl(d[0], (2 * qq + 1) * 16 + l15, 64);
      nb[5] = (__bf16)__shfl(d[1], (2 * qq + 1) * 16 + l15, 64);
      nb[6] = (__bf16)__shfl(d[2], (2 * qq + 1) * 16 + l15, 64);
      nb[7] = (__bf16)__shfl(d[3], (2 * qq + 1) * 16 + l15, 64);
      wb = nb;

      if (quad == 0) wsv[wv][l15] = part + nv;

      p0 = q0; p1 = q1; nv = nv2;
    }

    #pragma unroll
    for (int r = 0; r < 4; ++r)
      Qs[wv][(quad * 4 + r) * 16 + l15] = d[r];
  }
  __syncthreads();

  // ======== phase B: scan 16 supergroups of this batch (16 lanes) ========
  if (tid < 16) {
    const int r = tid;
    float h = 0.f;
    #pragma unroll 1
    for (int g = 0; g < 16; ++g) {
      hbgs[g][r] = h;
      const float4* Pr = (const float4*)&Qs[g][r * 16];
      float4 c0 = Pr[0], c1 = Pr[1], c2 = Pr[2], c3 = Pr[3];
      const float vc = wsv[g][r];
      float a0 = c0.x*__shfl(h, 0,16) + c0.y*__shfl(h, 1,16) + c0.z*__shfl(h, 2,16) + c0.w*__shfl(h, 3,16);
      float a1 = c1.x*__shfl(h, 4,16) + c1.y*__shfl(h, 5,16) + c1.z*__shfl(h, 6,16) + c1.w*__shfl(h, 7,16);
      float a2 = c2.x*__shfl(h, 8,16) + c2.y*__shfl(h, 9,16) + c2.z*__shfl(h,10,16) + c2.w*__shfl(h,11,16);
      float a3 = c3.x*__shfl(h,12,16) + c3.y*__shfl(h,13,16) + c3.z*__shfl(h,14,16) + c3.w*__shfl(h,15,16);
      h = vc + ((a0 + a1) + (a2 + a3));
    }
  }
  __syncthreads();

  // ======== phase C: replay chunks of supergroup g (256 threads) ========
  if (tid < 256) {
    const int g = tid >> 4;
    const int r = tid & 15;
    const int s = bx * 16 + g;
    float h = hbgs[g][r];

    float4 c0, c1, c2, c3; float vc;
    {
      const int chunk = s * SG;
      const float4* Pr = (const float4*)&P_ws[(size_t)chunk * 256 + r * 16];
      c0 = Pr[0]; c1 = Pr[1]; c2 = Pr[2]; c3 = Pr[3];
      vc = v_ws[(size_t)chunk * DS + r];
    }

    #pragma unroll 1
    for (int t = 0; t < SG; ++t) {
      const int chunk = s * SG + t;
      float4 d0, d1, d2, d3; float vc2;
      if (t < SG - 1) {
        const float4* Pr = (const float4*)&P_ws[(size_t)(chunk + 1) * 256 + r * 16];
        d0 = Pr[0]; d1 = Pr[1]; d2 = Pr[2]; d3 = Pr[3];
        vc2 = v_ws[(size_t)(chunk + 1) * DS + r];
      } else { d0 = c0; d1 = c1; d2 = c2; d3 = c3; vc2 = vc; }

      hb_ws[(size_t)chunk * DS + r] = h;
      float a0 = c0.x*__shfl(h, 0,16) + c0.y*__shfl(h, 1,16) + c0.z*__shfl(h, 2,16) + c0.w*__shfl(h, 3,16);
      float a1 = c1.x*__shfl(h, 4,16) + c1.y*__shfl(h, 5,16) + c1.z*__shfl(h, 6,16) + c1.w*__shfl(h, 7,16);
      float a2 = c2.x*__shfl(h, 8,16) + c2.y*__shfl(h, 9,16) + c2.z*__shfl(h,10,16) + c2.w*__shfl(h,11,16);
      float a3 = c3.x*__shfl(h,12,16) + c3.y*__shfl(h,13,16) + c3.z*__shfl(h,14,16) + c3.w*__shfl(h,15,16);
      h = vc + ((a0 + a1) + (a2 + a3));

      c0 = d0; c1 = d1; c2 = d2; c3 = d3; vc = vc2;
    }
  }
}

// ---------------------------------------------------------------------------
// G2 v4: same structure as v3 (16-t blocks, 1 cell/thread batch-issued
// phase 1, wave = r-column) but launch_bounds(256,6): ~85-VGPR cap so the
// compiler can HOLD the load batch (r9's (256,8)/64-cap produced VGPR=32
// with serialized loads + inflated traffic).  6 blocks/CU = 24 waves/CU.
// ---------------------------------------------------------------------------
__global__ __launch_bounds__(256, 6) void g2(
    const unsigned short* __restrict__ xb, const unsigned short* __restrict__ WCpk,
    const float* __restrict__ bC, const unsigned short* __restrict__ Wt_ws,
    const float* __restrict__ u_ws, const float* __restrict__ hb_ws,
    float* __restrict__ out)
{
  __shared__ float hsh[16][17];
  __shared__ float bCs[1024];
  const int tid  = threadIdx.x;
  const int lane = tid & 63;
  const int l15  = lane & 15;
  const int quad = lane >> 4;
  const int w    = tid >> 6;        // 0..3 = r-column block
  const int t0   = blockIdx.x * 16; // one chunk per block
  const int rc   = w;

  ((float4*)bCs)[tid] = ((const float4*)bC)[tid];

  // A-frag loads (consumed in phase 2) — issued early
  const bf16x8* xvp = (const bf16x8*)(xb + (size_t)(t0 + l15) * 64);
  bf16x8 a0 = xvp[quad];
  bf16x8 a1 = xvp[quad + 4];

  // ---- phase 1: 1 cell/thread, all loads batch-issued ----
  const int tl = tid >> 4, i = tid & 15;
  const int t  = t0 + tl;
  const uint4* wr = (const uint4*)(Wt_ws + (size_t)t * 256 + i * 16);
  uint4 wa = wr[0], wbv = wr[1];
  const float4* hp = (const float4*)(hb_ws + (size_t)blockIdx.x * DS); // chunk = blockIdx
  float4 h0 = hp[0], h1 = hp[1], h2 = hp[2], h3 = hp[3];
  float uu = u_ws[(size_t)t * DS + i];
  {
    float p0 = uu, p1 = 0.f, p2 = 0.f, p3 = 0.f;
    p0 = fmaf(bflo(wa.x),  h0.x, p0); p0 = fmaf(bfhi(wa.x),  h0.y, p0);
    p0 = fmaf(bflo(wa.y),  h0.z, p0); p0 = fmaf(bfhi(wa.y),  h0.w, p0);
    p1 = fmaf(bflo(wa.z),  h1.x, p1); p1 = fmaf(bfhi(wa.z),  h1.y, p1);
    p1 = fmaf(bflo(wa.w),  h1.z, p1); p1 = fmaf(bfhi(wa.w),  h1.w, p1);
    p2 = fmaf(bflo(wbv.x), h2.x, p2); p2 = fmaf(bfhi(wbv.x), h2.y, p2);
    p2 = fmaf(bflo(wbv.y), h2.z, p2); p2 = fmaf(bfhi(wbv.y), h2.w, p2);
    p3 = fmaf(bflo(wbv.z), h3.x, p3); p3 = fmaf(bfhi(wbv.z), h3.y, p3);
    p3 = fmaf(bflo(wbv.w), h3.z, p3); p3 = fmaf(bfhi(wbv.w), h3.w, p3);
    hsh[tl][i] = (p0 + p1) + (p2 + p3);
  }
  __syncthreads();

  // ---- phase 2: output projection, 1 r-column/wave, 1-deep prefetch ----
  f32x4 o0 = {0.f, 0.f, 0.f, 0.f};

  const bf16x8* cp = (const bf16x8*)(WCpk + (size_t)((0 * 4 + rc) * 64 + l15 * 4 + quad) * 16);
  bf16x8 c00 = cp[0], c01 = cp[1];
  #pragma unroll
  for (int n = 0; n < 16; ++n) {
    bf16x8 n00 = c00, n01 = c01;
    if (n < 15) {
      const bf16x8* np = (const bf16x8*)(WCpk + (size_t)(((n + 1) * 4 + rc) * 64 + l15 * 4 + quad) * 16);
      n00 = np[0]; n01 = np[1];
    }

    f32x4 ac0 = {0.f, 0.f, 0.f, 0.f};
    ac0 = __builtin_amdgcn_mfma_f32_16x16x32_bf16(a0, c00, ac0, 0, 0, 0);
    ac0 = __builtin_amdgcn_mfma_f32_16x16x32_bf16(a1, c01, ac0, 0, 0, 0);

    float hn[4];
    #pragma unroll
    for (int reg = 0; reg < 4; ++reg) hn[reg] = hsh[quad * 4 + reg][n];

    const float bc0 = bCs[n * 64 + rc * 16 + l15];
    #pragma unroll
    for (int reg = 0; reg < 4; ++reg)
      o0[reg] = fmaf(ac0[reg] + bc0, hn[reg], o0[reg]);

    c00 = n00; c01 = n01;
  }

  #pragma unroll
  for (int reg = 0; reg < 4; ++reg)
    out[(size_t)(t0 + quad * 4 + reg) * DM + rc * 16 + l15] = o0[reg];
}

// ---------------------------------------------------------------------------
extern "C" void kernel_launch(void* const* d_in, const int* in_sizes, int n_in,
                              void* d_out, int out_size, void* d_ws, size_t ws_size,
                              hipStream_t stream) {
  const float* x  = (const float*)d_in[0];
  const float* WA = (const float*)d_in[1];
  const float* bA = (const float*)d_in[2];
  const float* WB = (const float*)d_in[3];
  const float* bB = (const float*)d_in[4];
  const float* WC = (const float*)d_in[5];
  const float* bC = (const float*)d_in[6];
  float* out = (float*)d_out;

  float* ws     = (float*)d_ws;
  float* P_ws   = ws;                               // NCHT*256 (2 MB)
  float* v_ws   = P_ws   + (size_t)NCHT * 256;      // NCHT*16
  float* u_ws   = v_ws   + (size_t)NCHT * DS;       // BS*16
  float* Q_ws   = u_ws   + (size_t)BS * DS;         // NSG*256 (unused)
  float* w_ws   = Q_ws   + (size_t)NSG * 256;       // NSG*16  (unused)
  float* hbg_ws = w_ws   + (size_t)NSG * DS;        // NSG*16  (unused)
  float* hb_ws  = hbg_ws + (size_t)NSG * DS;        // NCHT*16
  unsigned short* xb    = (unsigned short*)(hb_ws + (size_t)NCHT * DS);
  unsigned short* WBApk = xb    + (size_t)BS * 64;  // 81920 ushorts (packed WB+WA)
  unsigned short* WCpk  = WBApk + 81920;            // 65536 ushorts (packed WC)
  unsigned short* Wt_ws = WCpk  + 65536;            // BS*256 (16.8 MB)

  k0_castw<<<576,      256, 0, stream>>>(WA, WB, WC, WBApk, WCpk);
  g1      <<<BS / 64,  256, 0, stream>>>(x, WBApk, bB, bA, xb, Wt_ws, u_ws, P_ws, v_ws);
  k3f     <<<1024,    1024, 0, stream>>>(P_ws, v_ws, hb_ws, Wt_ws, xb, u_ws);
  g2      <<<BS / 16,  256, 0, stream>>>(xb, WCpk, bC, Wt_ws, u_ws, hb_ws, out);
}